// Round 7
// baseline (248.690 us; speedup 1.0000x reference)
//
#include <hip/hip_runtime.h>

// QuantFinanceAttention: B=2, T=2048, C=1024, H=16, dk=64. fp32 I/O, bf16 MFMA internals.
// cvt(all) | QKV gemm (rope fused; V written pre-transposed [bh][d][t]) |
// flash v3 (barrier-free: direct-from-L2 K/V frags, key-split waves, one combine barrier) | proj.

typedef __bf16 bf16x8 __attribute__((ext_vector_type(8)));
typedef float f32x4 __attribute__((ext_vector_type(4)));
typedef float f32x16 __attribute__((ext_vector_type(16)));
typedef unsigned short u16x8 __attribute__((ext_vector_type(8)));

__device__ __forceinline__ unsigned short f2bf(float f) {
    union { float f; unsigned int u; } c; c.f = f;
    unsigned int u = c.u;
    unsigned int r = u + 0x7fffu + ((u >> 16) & 1u);  // RNE
    return (unsigned short)(r >> 16);
}
__device__ __forceinline__ void stage8_f32(unsigned short* dst, const float* src) {
    const float4 a = *(const float4*)src;
    const float4 b = *(const float4*)(src + 4);
    u16x8 v;
    v[0] = f2bf(a.x); v[1] = f2bf(a.y); v[2] = f2bf(a.z); v[3] = f2bf(a.w);
    v[4] = f2bf(b.x); v[5] = f2bf(b.y); v[6] = f2bf(b.z); v[7] = f2bf(b.w);
    *(u16x8*)dst = v;
}
__device__ __forceinline__ void async16(const unsigned short* g, unsigned short* l) {
    __builtin_amdgcn_global_load_lds(
        (const __attribute__((address_space(1))) void*)g,
        (__attribute__((address_space(3))) void*)l, 16, 0, 0);
}

// Fused fp32->bf16 convert. dst layout: [x(524288 g8) if hasX][Wq][Wk][Wv][Wo] (131072 g8 each).
__global__ __launch_bounds__(256) void cvt_all(
    const float* __restrict__ x, const float* __restrict__ Wq, const float* __restrict__ Wk,
    const float* __restrict__ Wv, const float* __restrict__ Wo,
    unsigned short* __restrict__ dst, int hasX, int n8)
{
    const int i = blockIdx.x * 256 + threadIdx.x;
    if (i >= n8) return;
    int r = i;
    const float* src; int off;
    const int xg = hasX ? 524288 : 0;
    if (r < xg) { src = x; off = r; }
    else {
        r -= xg;
        const int w = r >> 17, o = r & 131071;
        src = (w == 0) ? Wq : (w == 1) ? Wk : (w == 2) ? Wv : Wo;
        off = o;
    }
    stage8_f32(&dst[(size_t)i * 8], &src[(size_t)off * 8]);
}

// QKV: C[m,n] = sum_k A[m,k]*W[n,k], K=1024, 128x128 tile. W bf16 at base + z*1M.
// z<2 (Q,K): rope fused, out [z][bh][t][d]. z==2 (V): out transposed [bh][d][t] (b64 packs).
template<int A_BF16>
__global__ __launch_bounds__(256) void gemm_qkv(
    const void* __restrict__ Av, const unsigned short* __restrict__ Wb,
    unsigned short* __restrict__ outv)
{
    constexpr int K = 1024, BK = 32;
    __shared__ __align__(16) unsigned short As[128 * BK];
    __shared__ __align__(16) unsigned short Bs[128 * BK];
    const int tid = threadIdx.x;
    const int wid = tid >> 6, lane = tid & 63, g = lane >> 4, l = lane & 15;
    const int wm = (wid & 1) * 64, wn = (wid >> 1) * 64;
    const int m0 = blockIdx.y * 128, n0 = blockIdx.x * 128;
    const int z = blockIdx.z;
    const unsigned short* W = Wb + (size_t)z * 1048576;

    f32x4 acc[4][4];
#pragma unroll
    for (int i = 0; i < 4; ++i)
#pragma unroll
        for (int j = 0; j < 4; ++j) acc[i][j] = f32x4{0.f, 0.f, 0.f, 0.f};

    const int r = tid >> 2;
    const int c = (tid & 3) * 8;
    unsigned short* AsW = &As[wid * 512];
    unsigned short* BsW = &Bs[wid * 512];

    for (int k0 = 0; k0 < K; k0 += BK) {
        __syncthreads();
        if (A_BF16) {
            const unsigned short* A = (const unsigned short*)Av;
            async16(&A[(size_t)(m0 + r) * K + k0 + c], AsW);
            async16(&A[(size_t)(m0 + 64 + r) * K + k0 + c], AsW + 2048);
        } else {
            const float* A = (const float*)Av;
            stage8_f32(&As[tid * 8],        &A[(size_t)(m0 + r) * K + k0 + c]);
            stage8_f32(&As[tid * 8 + 2048], &A[(size_t)(m0 + 64 + r) * K + k0 + c]);
        }
        async16(&W[(size_t)(n0 + r) * K + k0 + c], BsW);
        async16(&W[(size_t)(n0 + 64 + r) * K + k0 + c], BsW + 2048);
        __syncthreads();

        bf16x8 af[4], bfr[4];
#pragma unroll
        for (int im = 0; im < 4; ++im) af[im]  = *(const bf16x8*)&As[(wm + im * 16 + l) * BK + g * 8];
#pragma unroll
        for (int in = 0; in < 4; ++in) bfr[in] = *(const bf16x8*)&Bs[(wn + in * 16 + l) * BK + g * 8];
#pragma unroll
        for (int im = 0; im < 4; ++im)
#pragma unroll
            for (int in = 0; in < 4; ++in)
                acc[im][in] = __builtin_amdgcn_mfma_f32_16x16x32_bf16(af[im], bfr[in], acc[im][in], 0, 0, 0);
    }

    unsigned short* outq = outv + (size_t)z * 4194304;
    if (z < 2) {
        float freq[2];
#pragma unroll
        for (int in = 0; in < 2; ++in)
            freq[in] = exp2f(-(float)(in * 16 + l) * 0.41524101186f);  // log2(10000)/32
#pragma unroll
        for (int im = 0; im < 4; ++im)
#pragma unroll
            for (int i = 0; i < 4; ++i) {
                const int m = m0 + wm + im * 16 + g * 4 + i;
                const int b = m >> 11, t = m & 2047;
#pragma unroll
                for (int in = 0; in < 2; ++in) {
                    const int n = n0 + wn + in * 16 + l;
                    const int h = n >> 6, d = n & 63;
                    const float ang = (float)t * freq[in];
                    const float cs = __cosf(ang), sn = __sinf(ang);
                    const float x1 = acc[im][in][i], x2 = acc[im][in + 2][i];
                    const size_t bidx = (((size_t)b * 16 + h) * 2048 + t) << 6;
                    outq[bidx + d]      = f2bf(x1 * cs - x2 * sn);
                    outq[bidx + d + 32] = f2bf(x2 * cs + x1 * sn);
                }
            }
    } else {
        // V transposed: [bh][d][t], 4 consecutive t per C-reg quad -> b64 stores
#pragma unroll
        for (int im = 0; im < 4; ++im)
#pragma unroll
            for (int in = 0; in < 4; ++in) {
                const int n = n0 + wn + in * 16 + l;
                const int h = n >> 6, d = n & 63;
                const int mb = m0 + wm + im * 16 + g * 4;
                const int bq = mb >> 11, t0 = mb & 2047;
                ushort4 pk;
                pk.x = f2bf(acc[im][in][0]); pk.y = f2bf(acc[im][in][1]);
                pk.z = f2bf(acc[im][in][2]); pk.w = f2bf(acc[im][in][3]);
                *(ushort4*)&outq[((size_t)(bq * 16 + h)) * 131072 + (size_t)d * 2048 + t0] = pk;
            }
    }
}

// Projection: C = A(bf16)[4096,1024] x Wo^T + bias, 64x128 tile -> 512 blocks (2/CU).
__global__ __launch_bounds__(256) void gemm_proj(
    const unsigned short* __restrict__ A, const unsigned short* __restrict__ W,
    float* __restrict__ out, const float* __restrict__ bias)
{
    constexpr int K = 1024, BK = 32;
    __shared__ __align__(16) unsigned short As[64 * BK];
    __shared__ __align__(16) unsigned short Bs[128 * BK];
    const int tid = threadIdx.x;
    const int wid = tid >> 6, lane = tid & 63, g = lane >> 4, l = lane & 15;
    const int wm = (wid & 1) * 32, wn = (wid >> 1) * 64;
    const int m0 = blockIdx.y * 64, n0 = blockIdx.x * 128;

    f32x4 acc[2][4];
#pragma unroll
    for (int i = 0; i < 2; ++i)
#pragma unroll
        for (int j = 0; j < 4; ++j) acc[i][j] = f32x4{0.f, 0.f, 0.f, 0.f};

    const int r = tid >> 2;
    const int c = (tid & 3) * 8;
    unsigned short* AsW = &As[wid * 512];
    unsigned short* BsW = &Bs[wid * 512];

    for (int k0 = 0; k0 < K; k0 += BK) {
        __syncthreads();
        async16(&A[(size_t)(m0 + r) * K + k0 + c], AsW);
        async16(&W[(size_t)(n0 + r) * K + k0 + c], BsW);
        async16(&W[(size_t)(n0 + 64 + r) * K + k0 + c], BsW + 2048);
        __syncthreads();

        bf16x8 af[2], bfr[4];
#pragma unroll
        for (int im = 0; im < 2; ++im) af[im]  = *(const bf16x8*)&As[(wm + im * 16 + l) * BK + g * 8];
#pragma unroll
        for (int in = 0; in < 4; ++in) bfr[in] = *(const bf16x8*)&Bs[(wn + in * 16 + l) * BK + g * 8];
#pragma unroll
        for (int im = 0; im < 2; ++im)
#pragma unroll
            for (int in = 0; in < 4; ++in)
                acc[im][in] = __builtin_amdgcn_mfma_f32_16x16x32_bf16(af[im], bfr[in], acc[im][in], 0, 0, 0);
    }

#pragma unroll
    for (int im = 0; im < 2; ++im)
#pragma unroll
        for (int in = 0; in < 4; ++in) {
            const int n = n0 + wn + in * 16 + l;
#pragma unroll
            for (int i = 0; i < 4; ++i) {
                const int m = m0 + wm + im * 16 + g * 4 + i;
                out[(size_t)m * 1024 + n] = acc[im][in][i] + bias[n];
            }
        }
}

// Flash v3: 2048 blocks x 128 threads. Block = (bh, 32-q tile); the 2 waves split the
// KEY dimension (wave w: 32-key chunks w, w+2, ...). Constant-max softmax makes partials
// additive -> no barriers in the loop; single combine barrier at the end.
// K/V fragments read DIRECTLY from global (L2-resident); only P round-trips through LDS.
__global__ __launch_bounds__(128) void flash_attn(
    const unsigned short* __restrict__ Q, const unsigned short* __restrict__ Kg,
    const unsigned short* __restrict__ VT, const float* __restrict__ sbias,
    const float* __restrict__ sw, unsigned short* __restrict__ attn)
{
    constexpr int T = 2048;
    __shared__ __align__(16) unsigned short Ps[2][32 * 40];  // per-wave P [q][key], 5.1KB
    __shared__ float Cmb[48 * 64];                            // combine buffer, 12KB
    const int tid = threadIdx.x, wid = tid >> 6, lane = tid & 63;
    const int hl = lane & 31, hh = lane >> 5;
    // XCD-aware mapping: 4 heads per id%8 slice (per-XCD K/V ~2.1MB < 4MB L2); longest-first.
    const int id = blockIdx.x;
    const int k8 = id >> 3;
    const int bh = (id & 7) * 4 + (k8 >> 6);
    const int p  = 63 - (k8 & 63);                 // q-tile index, 0..63
    const int b = bh >> 4, h = bh & 15;
    const size_t base = (size_t)bh * T * 64;       // Q/K: [t][d]
    const size_t vtb  = (size_t)bh * 64 * T;       // V^T: [d][t]
    const float bias = sbias[h];
    const float* swb = sw + b * T;

    bf16x8 onef;
#pragma unroll
    for (int j = 0; j < 8; ++j) onef[j] = (__bf16)1.0f;

    const int q0 = p * 32;
    bf16x8 qf[4];
#pragma unroll
    for (int ks = 0; ks < 4; ++ks)
        qf[ks] = *(const bf16x8*)&Q[base + (size_t)(q0 + hl) * 64 + ks * 16 + hh * 8];

    f32x16 oacc[2], lrow;
#pragma unroll
    for (int r = 0; r < 16; ++r) { oacc[0][r] = 0.f; oacc[1][r] = 0.f; lrow[r] = 0.f; }

    // row offsets of the 32x32 C-layout (per lane): row = (r&3) + 8*(r>>2) + 4*hh
    u16x8 kfr[4], vfr[2][2];
    if (wid <= p) {   // preload first chunk's fragments
        const int k0 = wid * 32;
#pragma unroll
        for (int ks = 0; ks < 4; ++ks)
            kfr[ks] = *(const u16x8*)&Kg[base + (size_t)(k0 + hl) * 64 + ks * 16 + hh * 8];
#pragma unroll
        for (int dt = 0; dt < 2; ++dt)
#pragma unroll
            for (int ks = 0; ks < 2; ++ks)
                vfr[dt][ks] = *(const u16x8*)&VT[vtb + (size_t)(dt * 32 + hl) * T + k0 + ks * 16 + hh * 8];
    }

    for (int ch = wid; ch <= p; ch += 2) {
        const int k0 = ch * 32;
        const int kc = k0 + hl;
        const float w = swb[kc];
        const float a = w * 0.125f, cst = w * bias;

        // S = Q K^T (32q x 32k), B-frag straight from registers (loaded from L2)
        f32x16 sx;
#pragma unroll
        for (int r = 0; r < 16; ++r) sx[r] = 0.f;
#pragma unroll
        for (int ks = 0; ks < 4; ++ks)
            sx = __builtin_amdgcn_mfma_f32_32x32x16_bf16(qf[ks], (bf16x8)kfr[ks], sx, 0, 0, 0);

        // prefetch next chunk's K frags (kfr dead after the mfmas above)
        if (ch + 2 <= p) {
            const int kn = k0 + 64;
#pragma unroll
            for (int ks = 0; ks < 4; ++ks)
                kfr[ks] = *(const u16x8*)&Kg[base + (size_t)(kn + hl) * 64 + ks * 16 + hh * 8];
        }

        // p = exp((s*SCALE + bias)*w), causal mask (exp -> 0 above diagonal)
#pragma unroll
        for (int r = 0; r < 16; ++r) {
            const int row = (r & 3) + 8 * (r >> 2) + 4 * hh;
            float xv = sx[r] * a + cst;
            xv = (kc <= q0 + row) ? xv : -1e30f;
            Ps[wid][row * 40 + hl] = f2bf(__expf(xv));
        }
        __threadfence_block();
        bf16x8 pf[2];
        pf[0] = *(const bf16x8*)&Ps[wid][hl * 40 + hh * 8];
        pf[1] = *(const bf16x8*)&Ps[wid][hl * 40 + 16 + hh * 8];

        // rowsum via ones-MFMA; O += P V
        f32x16 ls;
#pragma unroll
        for (int r = 0; r < 16; ++r) ls[r] = 0.f;
        ls = __builtin_amdgcn_mfma_f32_32x32x16_bf16(pf[0], onef, ls, 0, 0, 0);
        ls = __builtin_amdgcn_mfma_f32_32x32x16_bf16(pf[1], onef, ls, 0, 0, 0);
#pragma unroll
        for (int r = 0; r < 16; ++r) lrow[r] += ls[r];

#pragma unroll
        for (int ks = 0; ks < 2; ++ks)
#pragma unroll
            for (int dt = 0; dt < 2; ++dt)
                oacc[dt] = __builtin_amdgcn_mfma_f32_32x32x16_bf16(pf[ks], (bf16x8)vfr[dt][ks], oacc[dt], 0, 0, 0);

        // prefetch next chunk's V frags (vfr dead after the mfmas above)
        if (ch + 2 <= p) {
            const int kn = k0 + 64;
#pragma unroll
            for (int dt = 0; dt < 2; ++dt)
#pragma unroll
                for (int ks = 0; ks < 2; ++ks)
                    vfr[dt][ks] = *(const u16x8*)&VT[vtb + (size_t)(dt * 32 + hl) * T + kn + ks * 16 + hh * 8];
        }
    }

    // combine the two waves' partials (additive: constant-max softmax)
    if (wid == 1) {
#pragma unroll
        for (int dt = 0; dt < 2; ++dt)
#pragma unroll
            for (int r = 0; r < 16; ++r) Cmb[(dt * 16 + r) * 64 + lane] = oacc[dt][r];
#pragma unroll
        for (int r = 0; r < 16; ++r) Cmb[2048 + r * 64 + lane] = lrow[r];
    }
    __syncthreads();
    if (wid == 0) {
#pragma unroll
        for (int r = 0; r < 16; ++r) {
            const float li = 1.0f / (lrow[r] + Cmb[2048 + r * 64 + lane]);
            const int row = (r & 3) + 8 * (r >> 2) + 4 * hh;
            const int qr = q0 + row;
#pragma unroll
            for (int dt = 0; dt < 2; ++dt) {
                const float ov = oacc[dt][r] + Cmb[(dt * 16 + r) * 64 + lane];
                attn[(size_t)(b * T + qr) * 1024 + h * 64 + dt * 32 + hl] = f2bf(ov * li);
            }
        }
    }
}

extern "C" void kernel_launch(void* const* d_in, const int* in_sizes, int n_in,
                              void* d_out, int out_size, void* d_ws, size_t ws_size,
                              hipStream_t stream) {
    const float* x  = (const float*)d_in[0];
    const float* Wq = (const float*)d_in[1];
    const float* Wk = (const float*)d_in[2];
    const float* Wv = (const float*)d_in[3];
    const float* Wo = (const float*)d_in[4];
    const float* bo = (const float*)d_in[5];
    const float* sb = (const float*)d_in[6];
    const float* sw = (const float*)d_in[7];

    const size_t QKV_SZ = 4194304;   // shorts per q/k/v tensor
    const size_t W_SZ   = 1048576;   // shorts per weight matrix
    unsigned short* ws16 = (unsigned short*)d_ws;
    const bool big = ws_size >= 2 * (4 * QKV_SZ + 4 * W_SZ);  // 41.9 MB

    if (big) {
        unsigned short* xb    = ws16;            // x bf16
        unsigned short* Wb3   = xb + QKV_SZ;     // Wq,Wk,Wv
        unsigned short* Wob   = Wb3 + 3 * W_SZ;  // Wo
        unsigned short* qkv   = Wob + W_SZ;      // q,k (head-major), v^T
        unsigned short* attnb = xb;              // overlay x (dead after QKV gemm)

        cvt_all<<<4096, 256, 0, stream>>>(x, Wq, Wk, Wv, Wo, xb, 1, 1048576);
        gemm_qkv<1><<<dim3(8, 32, 3), 256, 0, stream>>>(xb, Wb3, qkv);
        flash_attn<<<2048, 128, 0, stream>>>(qkv, qkv + QKV_SZ, qkv + 2 * QKV_SZ,
                                             sb, sw, attnb);
        gemm_proj<<<dim3(8, 64), 256, 0, stream>>>(attnb, Wob, (float*)d_out, bo);
    } else {                                     // 33.6 MB fallback
        unsigned short* qkv   = ws16;
        unsigned short* attnb = qkv + 3 * QKV_SZ;
        unsigned short* Wb3   = attnb;           // overlay attn (dead until flash)
        unsigned short* Wob   = qkv;             // overlay q (dead after flash)

        cvt_all<<<1536, 256, 0, stream>>>(x, Wq, Wk, Wv, Wo, Wb3, 0, 393216);
        gemm_qkv<0><<<dim3(8, 32, 3), 256, 0, stream>>>(x, Wb3, qkv);
        flash_attn<<<2048, 128, 0, stream>>>(qkv, qkv + QKV_SZ, qkv + 2 * QKV_SZ,
                                             sb, sw, attnb);
        cvt_all<<<512, 256, 0, stream>>>(x, Wo, Wo, Wo, Wo, Wob, 0, 131072);
        gemm_proj<<<dim3(8, 64), 256, 0, stream>>>(attnb, Wob, (float*)d_out, bo);
    }
}

// Round 8
// 224.662 us; speedup vs baseline: 1.1070x; 1.1070x over previous
//
#include <hip/hip_runtime.h>

// QuantFinanceAttention: B=2, T=2048, C=1024, H=16, dk=64. fp32 I/O, bf16 MFMA internals.
// cvt(all) | QKV gemm (rope fused; V written pre-transposed [bh][d][t]) |
// flash v4 (staged 64-key rounds, keys-split waves, longest-first, 6 blocks/CU) | proj.

typedef __bf16 bf16x8 __attribute__((ext_vector_type(8)));
typedef float f32x4 __attribute__((ext_vector_type(4)));
typedef float f32x16 __attribute__((ext_vector_type(16)));
typedef unsigned short u16x8 __attribute__((ext_vector_type(8)));

__device__ __forceinline__ unsigned short f2bf(float f) {
    union { float f; unsigned int u; } c; c.f = f;
    unsigned int u = c.u;
    unsigned int r = u + 0x7fffu + ((u >> 16) & 1u);  // RNE
    return (unsigned short)(r >> 16);
}
__device__ __forceinline__ void stage8_f32(unsigned short* dst, const float* src) {
    const float4 a = *(const float4*)src;
    const float4 b = *(const float4*)(src + 4);
    u16x8 v;
    v[0] = f2bf(a.x); v[1] = f2bf(a.y); v[2] = f2bf(a.z); v[3] = f2bf(a.w);
    v[4] = f2bf(b.x); v[5] = f2bf(b.y); v[6] = f2bf(b.z); v[7] = f2bf(b.w);
    *(u16x8*)dst = v;
}
__device__ __forceinline__ void async16(const unsigned short* g, unsigned short* l) {
    __builtin_amdgcn_global_load_lds(
        (const __attribute__((address_space(1))) void*)g,
        (__attribute__((address_space(3))) void*)l, 16, 0, 0);
}

// Fused fp32->bf16 convert. dst layout: [x(524288 g8) if hasX][Wq][Wk][Wv][Wo] (131072 g8 each).
__global__ __launch_bounds__(256) void cvt_all(
    const float* __restrict__ x, const float* __restrict__ Wq, const float* __restrict__ Wk,
    const float* __restrict__ Wv, const float* __restrict__ Wo,
    unsigned short* __restrict__ dst, int hasX, int n8)
{
    const int i = blockIdx.x * 256 + threadIdx.x;
    if (i >= n8) return;
    int r = i;
    const float* src; int off;
    const int xg = hasX ? 524288 : 0;
    if (r < xg) { src = x; off = r; }
    else {
        r -= xg;
        const int w = r >> 17, o = r & 131071;
        src = (w == 0) ? Wq : (w == 1) ? Wk : (w == 2) ? Wv : Wo;
        off = o;
    }
    stage8_f32(&dst[(size_t)i * 8], &src[(size_t)off * 8]);
}

// QKV: C[m,n] = sum_k A[m,k]*W[n,k], K=1024, 128x128 tile. W bf16 at base + z*1M.
// z<2 (Q,K): rope fused, out [z][bh][t][d]. z==2 (V): out transposed [bh][d][t] (b64 packs).
template<int A_BF16>
__global__ __launch_bounds__(256) void gemm_qkv(
    const void* __restrict__ Av, const unsigned short* __restrict__ Wb,
    unsigned short* __restrict__ outv)
{
    constexpr int K = 1024, BK = 32;
    __shared__ __align__(16) unsigned short As[128 * BK];
    __shared__ __align__(16) unsigned short Bs[128 * BK];
    const int tid = threadIdx.x;
    const int wid = tid >> 6, lane = tid & 63, g = lane >> 4, l = lane & 15;
    const int wm = (wid & 1) * 64, wn = (wid >> 1) * 64;
    const int m0 = blockIdx.y * 128, n0 = blockIdx.x * 128;
    const int z = blockIdx.z;
    const unsigned short* W = Wb + (size_t)z * 1048576;

    f32x4 acc[4][4];
#pragma unroll
    for (int i = 0; i < 4; ++i)
#pragma unroll
        for (int j = 0; j < 4; ++j) acc[i][j] = f32x4{0.f, 0.f, 0.f, 0.f};

    const int r = tid >> 2;
    const int c = (tid & 3) * 8;
    unsigned short* AsW = &As[wid * 512];
    unsigned short* BsW = &Bs[wid * 512];

    for (int k0 = 0; k0 < K; k0 += BK) {
        __syncthreads();
        if (A_BF16) {
            const unsigned short* A = (const unsigned short*)Av;
            async16(&A[(size_t)(m0 + r) * K + k0 + c], AsW);
            async16(&A[(size_t)(m0 + 64 + r) * K + k0 + c], AsW + 2048);
        } else {
            const float* A = (const float*)Av;
            stage8_f32(&As[tid * 8],        &A[(size_t)(m0 + r) * K + k0 + c]);
            stage8_f32(&As[tid * 8 + 2048], &A[(size_t)(m0 + 64 + r) * K + k0 + c]);
        }
        async16(&W[(size_t)(n0 + r) * K + k0 + c], BsW);
        async16(&W[(size_t)(n0 + 64 + r) * K + k0 + c], BsW + 2048);
        __syncthreads();

        bf16x8 af[4], bfr[4];
#pragma unroll
        for (int im = 0; im < 4; ++im) af[im]  = *(const bf16x8*)&As[(wm + im * 16 + l) * BK + g * 8];
#pragma unroll
        for (int in = 0; in < 4; ++in) bfr[in] = *(const bf16x8*)&Bs[(wn + in * 16 + l) * BK + g * 8];
#pragma unroll
        for (int im = 0; im < 4; ++im)
#pragma unroll
            for (int in = 0; in < 4; ++in)
                acc[im][in] = __builtin_amdgcn_mfma_f32_16x16x32_bf16(af[im], bfr[in], acc[im][in], 0, 0, 0);
    }

    unsigned short* outq = outv + (size_t)z * 4194304;
    if (z < 2) {
        float freq[2];
#pragma unroll
        for (int in = 0; in < 2; ++in)
            freq[in] = exp2f(-(float)(in * 16 + l) * 0.41524101186f);  // log2(10000)/32
#pragma unroll
        for (int im = 0; im < 4; ++im)
#pragma unroll
            for (int i = 0; i < 4; ++i) {
                const int m = m0 + wm + im * 16 + g * 4 + i;
                const int b = m >> 11, t = m & 2047;
#pragma unroll
                for (int in = 0; in < 2; ++in) {
                    const int n = n0 + wn + in * 16 + l;
                    const int h = n >> 6, d = n & 63;
                    const float ang = (float)t * freq[in];
                    const float cs = __cosf(ang), sn = __sinf(ang);
                    const float x1 = acc[im][in][i], x2 = acc[im][in + 2][i];
                    const size_t bidx = (((size_t)b * 16 + h) * 2048 + t) << 6;
                    outq[bidx + d]      = f2bf(x1 * cs - x2 * sn);
                    outq[bidx + d + 32] = f2bf(x2 * cs + x1 * sn);
                }
            }
    } else {
        // V transposed: [bh][d][t], 4 consecutive t per C-reg quad -> b64 stores
#pragma unroll
        for (int im = 0; im < 4; ++im)
#pragma unroll
            for (int in = 0; in < 4; ++in) {
                const int n = n0 + wn + in * 16 + l;
                const int h = n >> 6, d = n & 63;
                const int mb = m0 + wm + im * 16 + g * 4;
                const int bq = mb >> 11, t0 = mb & 2047;
                ushort4 pk;
                pk.x = f2bf(acc[im][in][0]); pk.y = f2bf(acc[im][in][1]);
                pk.z = f2bf(acc[im][in][2]); pk.w = f2bf(acc[im][in][3]);
                *(ushort4*)&outq[((size_t)(bq * 16 + h)) * 131072 + (size_t)d * 2048 + t0] = pk;
            }
    }
}

// Projection: C = A(bf16)[4096,1024] x Wo^T + bias, 64x128 tile -> 512 blocks (2/CU).
__global__ __launch_bounds__(256) void gemm_proj(
    const unsigned short* __restrict__ A, const unsigned short* __restrict__ W,
    float* __restrict__ out, const float* __restrict__ bias)
{
    constexpr int K = 1024, BK = 32;
    __shared__ __align__(16) unsigned short As[64 * BK];
    __shared__ __align__(16) unsigned short Bs[128 * BK];
    const int tid = threadIdx.x;
    const int wid = tid >> 6, lane = tid & 63, g = lane >> 4, l = lane & 15;
    const int wm = (wid & 1) * 32, wn = (wid >> 1) * 64;
    const int m0 = blockIdx.y * 64, n0 = blockIdx.x * 128;

    f32x4 acc[2][4];
#pragma unroll
    for (int i = 0; i < 2; ++i)
#pragma unroll
        for (int j = 0; j < 4; ++j) acc[i][j] = f32x4{0.f, 0.f, 0.f, 0.f};

    const int r = tid >> 2;
    const int c = (tid & 3) * 8;
    unsigned short* AsW = &As[wid * 512];
    unsigned short* BsW = &Bs[wid * 512];

    for (int k0 = 0; k0 < K; k0 += BK) {
        __syncthreads();
        async16(&A[(size_t)(m0 + r) * K + k0 + c], AsW);
        async16(&W[(size_t)(n0 + r) * K + k0 + c], BsW);
        async16(&W[(size_t)(n0 + 64 + r) * K + k0 + c], BsW + 2048);
        __syncthreads();

        bf16x8 af[2], bfr[4];
#pragma unroll
        for (int im = 0; im < 2; ++im) af[im]  = *(const bf16x8*)&As[(wm + im * 16 + l) * BK + g * 8];
#pragma unroll
        for (int in = 0; in < 4; ++in) bfr[in] = *(const bf16x8*)&Bs[(wn + in * 16 + l) * BK + g * 8];
#pragma unroll
        for (int im = 0; im < 2; ++im)
#pragma unroll
            for (int in = 0; in < 4; ++in)
                acc[im][in] = __builtin_amdgcn_mfma_f32_16x16x32_bf16(af[im], bfr[in], acc[im][in], 0, 0, 0);
    }

#pragma unroll
    for (int im = 0; im < 2; ++im)
#pragma unroll
        for (int in = 0; in < 4; ++in) {
            const int n = n0 + wn + in * 16 + l;
#pragma unroll
            for (int i = 0; i < 4; ++i) {
                const int m = m0 + wm + im * 16 + g * 4 + i;
                out[(size_t)m * 1024 + n] = acc[im][in][i] + bias[n];
            }
        }
}

// Flash v4: 2048 blocks x 128 threads, block = (bh, 32q strip p), globally longest-first.
// Rounds of 64 keys staged coalesced to LDS (register prefetch); the 2 waves split each
// round's keys (wave w: [32w,32w+32)). Constant-max softmax -> partials additive; one
// combine at the end. LDS 23.5KB -> 6 blocks/CU (12 waves/CU).
__global__ __launch_bounds__(128) void flash_attn(
    const unsigned short* __restrict__ Q, const unsigned short* __restrict__ Kg,
    const unsigned short* __restrict__ VT, const float* __restrict__ sbias,
    const float* __restrict__ sw, unsigned short* __restrict__ attn)
{
    constexpr int T = 2048;
    __shared__ __align__(16) unsigned short Mem[64 * 72 * 2 + 2 * 32 * 40];
    unsigned short* Ks  = Mem;              // [key][d]  64 x 72
    unsigned short* VsT = Mem + 64 * 72;    // [d][key]  64 x 72
    unsigned short* Ps  = Mem + 2 * 64 * 72;// per-wave [q][key] 2 x 32 x 40
    float* Cmb = (float*)Mem;               // combine overlay (12KB over dead K/V)

    const int tid = threadIdx.x, wid = tid >> 6, lane = tid & 63;
    const int hl = lane & 31, hh = lane >> 5;
    const int id = blockIdx.x;
    const int p  = 63 - (id >> 5);          // globally longest-first
    const int bh = id & 31, b = bh >> 4, h = bh & 15;
    const size_t base = (size_t)bh * T * 64;   // Q/K: [t][d]
    const size_t vtb  = (size_t)bh * 64 * T;   // V^T: [d][t]
    const float bias = sbias[h];
    const float* swb = sw + b * T;

    bf16x8 onef;
#pragma unroll
    for (int j = 0; j < 8; ++j) onef[j] = (__bf16)1.0f;

    const int q0 = p * 32;
    bf16x8 qf[4];
#pragma unroll
    for (int ks = 0; ks < 4; ++ks)
        qf[ks] = *(const bf16x8*)&Q[base + (size_t)(q0 + hl) * 64 + ks * 16 + hh * 8];

    f32x16 oacc[2], lrow;
#pragma unroll
    for (int r = 0; r < 16; ++r) { oacc[0][r] = 0.f; oacc[1][r] = 0.f; lrow[r] = 0.f; }

    // prefetch round 0 (coalesced: 8KB K + 8KB V via 128 thr x 4 x 16B)
    u16x8 kpre[4], vpre[4];
#pragma unroll
    for (int s = 0; s < 4; ++s) {
        const int ci = s * 128 + tid, rr = ci >> 3, c8 = (ci & 7) * 8;
        kpre[s] = *(const u16x8*)&Kg[base + (size_t)rr * 64 + c8];
        vpre[s] = *(const u16x8*)&VT[vtb + (size_t)rr * T + c8];
    }

    unsigned short* Pw = Ps + wid * 32 * 40;
    const int rounds = (p + 2) >> 1;
    for (int rd = 0; rd < rounds; ++rd) {
        const int k0 = rd * 64;
        __syncthreads();
#pragma unroll
        for (int s = 0; s < 4; ++s) {        // regs -> LDS
            const int ci = s * 128 + tid, rr = ci >> 3, c8 = (ci & 7) * 8;
            *(u16x8*)&Ks[rr * 72 + c8]  = kpre[s];
            *(u16x8*)&VsT[rr * 72 + c8] = vpre[s];
        }
        __syncthreads();
        if (rd + 1 < rounds) {               // issue next-round loads; overlap compute
            const int k1 = k0 + 64;
#pragma unroll
            for (int s = 0; s < 4; ++s) {
                const int ci = s * 128 + tid, rr = ci >> 3, c8 = (ci & 7) * 8;
                kpre[s] = *(const u16x8*)&Kg[base + (size_t)(k1 + rr) * 64 + c8];
                vpre[s] = *(const u16x8*)&VT[vtb + (size_t)rr * T + k1 + c8];
            }
        }

        const int kc = k0 + wid * 32 + hl;   // this wave's key column
        const float w = swb[kc];
        const float a = w * 0.125f, cst = w * bias;

        // S = Q K^T (32q x 32k)
        f32x16 sx;
#pragma unroll
        for (int r = 0; r < 16; ++r) sx[r] = 0.f;
#pragma unroll
        for (int ks = 0; ks < 4; ++ks) {
            const bf16x8 kf = *(const bf16x8*)&Ks[(wid * 32 + hl) * 72 + ks * 16 + hh * 8];
            sx = __builtin_amdgcn_mfma_f32_32x32x16_bf16(qf[ks], kf, sx, 0, 0, 0);
        }

        // p = exp((s*SCALE + bias)*w), causal mask (exp -> 0 above diagonal)
#pragma unroll
        for (int r = 0; r < 16; ++r) {
            const int row = (r & 3) + 8 * (r >> 2) + 4 * hh;
            float xv = sx[r] * a + cst;
            xv = (kc <= q0 + row) ? xv : -1e30f;
            Pw[row * 40 + hl] = f2bf(__expf(xv));
        }
        __threadfence_block();
        bf16x8 pf[2];
        pf[0] = *(const bf16x8*)&Pw[hl * 40 + hh * 8];
        pf[1] = *(const bf16x8*)&Pw[hl * 40 + 16 + hh * 8];

        // rowsum via ones-MFMA (C rows match oacc rows)
        f32x16 ls;
#pragma unroll
        for (int r = 0; r < 16; ++r) ls[r] = 0.f;
        ls = __builtin_amdgcn_mfma_f32_32x32x16_bf16(pf[0], onef, ls, 0, 0, 0);
        ls = __builtin_amdgcn_mfma_f32_32x32x16_bf16(pf[1], onef, ls, 0, 0, 0);
#pragma unroll
        for (int r = 0; r < 16; ++r) lrow[r] += ls[r];

        // O += P V : B-frag from staged V^T at this wave's key offset
#pragma unroll
        for (int ks = 0; ks < 2; ++ks)
#pragma unroll
            for (int dt = 0; dt < 2; ++dt) {
                const bf16x8 vf = *(const bf16x8*)&VsT[(dt * 32 + hl) * 72 + wid * 32 + ks * 16 + hh * 8];
                oacc[dt] = __builtin_amdgcn_mfma_f32_32x32x16_bf16(pf[ks], vf, oacc[dt], 0, 0, 0);
            }
    }

    // combine the two waves' partials (additive under constant-max softmax)
    __syncthreads();                          // K/V LDS dead -> safe to overlay Cmb
    if (wid == 1) {
#pragma unroll
        for (int dt = 0; dt < 2; ++dt)
#pragma unroll
            for (int r = 0; r < 16; ++r) Cmb[(dt * 16 + r) * 64 + lane] = oacc[dt][r];
#pragma unroll
        for (int r = 0; r < 16; ++r) Cmb[2048 + r * 64 + lane] = lrow[r];
    }
    __syncthreads();
    if (wid == 0) {
#pragma unroll
        for (int r = 0; r < 16; ++r) {
            const float li = 1.0f / (lrow[r] + Cmb[2048 + r * 64 + lane]);
            const int row = (r & 3) + 8 * (r >> 2) + 4 * hh;
            const int qr = q0 + row;
#pragma unroll
            for (int dt = 0; dt < 2; ++dt) {
                const float ov = oacc[dt][r] + Cmb[(dt * 16 + r) * 64 + lane];
                attn[(size_t)(b * T + qr) * 1024 + h * 64 + dt * 32 + hl] = f2bf(ov * li);
            }
        }
    }
}

extern "C" void kernel_launch(void* const* d_in, const int* in_sizes, int n_in,
                              void* d_out, int out_size, void* d_ws, size_t ws_size,
                              hipStream_t stream) {
    const float* x  = (const float*)d_in[0];
    const float* Wq = (const float*)d_in[1];
    const float* Wk = (const float*)d_in[2];
    const float* Wv = (const float*)d_in[3];
    const float* Wo = (const float*)d_in[4];
    const float* bo = (const float*)d_in[5];
    const float* sb = (const float*)d_in[6];
    const float* sw = (const float*)d_in[7];

    const size_t QKV_SZ = 4194304;   // shorts per q/k/v tensor
    const size_t W_SZ   = 1048576;   // shorts per weight matrix
    unsigned short* ws16 = (unsigned short*)d_ws;
    const bool big = ws_size >= 2 * (4 * QKV_SZ + 4 * W_SZ);  // 41.9 MB

    if (big) {
        unsigned short* xb    = ws16;            // x bf16
        unsigned short* Wb3   = xb + QKV_SZ;     // Wq,Wk,Wv
        unsigned short* Wob   = Wb3 + 3 * W_SZ;  // Wo
        unsigned short* qkv   = Wob + W_SZ;      // q,k (head-major), v^T
        unsigned short* attnb = xb;              // overlay x (dead after QKV gemm)

        cvt_all<<<4096, 256, 0, stream>>>(x, Wq, Wk, Wv, Wo, xb, 1, 1048576);
        gemm_qkv<1><<<dim3(8, 32, 3), 256, 0, stream>>>(xb, Wb3, qkv);
        flash_attn<<<2048, 128, 0, stream>>>(qkv, qkv + QKV_SZ, qkv + 2 * QKV_SZ,
                                             sb, sw, attnb);
        gemm_proj<<<dim3(8, 64), 256, 0, stream>>>(attnb, Wob, (float*)d_out, bo);
    } else {                                     // 33.6 MB fallback
        unsigned short* qkv   = ws16;
        unsigned short* attnb = qkv + 3 * QKV_SZ;
        unsigned short* Wb3   = attnb;           // overlay attn (dead until flash)
        unsigned short* Wob   = qkv;             // overlay q (dead after flash)

        cvt_all<<<1536, 256, 0, stream>>>(x, Wq, Wk, Wv, Wo, Wb3, 0, 393216);
        gemm_qkv<0><<<dim3(8, 32, 3), 256, 0, stream>>>(x, Wb3, qkv);
        flash_attn<<<2048, 128, 0, stream>>>(qkv, qkv + QKV_SZ, qkv + 2 * QKV_SZ,
                                             sb, sw, attnb);
        cvt_all<<<512, 256, 0, stream>>>(x, Wo, Wo, Wo, Wo, Wob, 0, 131072);
        gemm_proj<<<dim3(8, 64), 256, 0, stream>>>(attnb, Wob, (float*)d_out, bo);
    }
}